// Round 1
// baseline (551.867 us; speedup 1.0000x reference)
//
#include <hip/hip_runtime.h>
#include <hip/hip_bf16.h>
#include <stdint.h>

// Problem constants: B=4, S=2048, IN=OUT=4096, R=16, SCALING=2.0
#define M_DIM 8192   // B*S
#define N_DIM 4096   // OUT
#define K_DIM 4096   // IN
#define R_DIM 16
#define NT    64     // K_DIM / 64 K-tiles

#define WPREP_BLOCKS 4096   // one W-row per block
#define CAST_BLOCKS  4096   // 2048 float4 per block

typedef __attribute__((ext_vector_type(8))) short bf16x8;   // A/B frag (4 VGPRs)
typedef __attribute__((ext_vector_type(4))) float f32x4;    // C/D frag

__device__ __forceinline__ unsigned short f2bf(float f) {
  union { float f; unsigned int u; } v; v.f = f;
  unsigned int r = 0x7FFFu + ((v.u >> 16) & 1u);   // RNE
  return (unsigned short)((v.u + r) >> 16);
}

__device__ __forceinline__ void gload16(const unsigned short* g, unsigned short* l) {
  __builtin_amdgcn_global_load_lds(
      (const __attribute__((address_space(1))) void*)g,
      (__attribute__((address_space(3))) void*)l,
      16, 0, 0);
}

// ---- merged prep, no-LDS / no-barrier structure (unchanged, verified) ----
__global__ void __launch_bounds__(256) prep_kernel(
    const float4* __restrict__ x4, ushort4* __restrict__ xbf4,
    const float4* __restrict__ W4, const float4* __restrict__ Aw4,
    const float* __restrict__ Bw, const float* __restrict__ mag,
    ushort4* __restrict__ wbf4, float* __restrict__ scale) {
  const int tid = threadIdx.x;

  if (blockIdx.x >= WPREP_BLOCKS) {
    const int base = (blockIdx.x - WPREP_BLOCKS) * 2048 + tid;
    #pragma unroll
    for (int u = 0; u < 8; ++u) {
      const int i = base + u * 256;
      float4 f = x4[i];
      ushort4 o;
      o.x = f2bf(f.x); o.y = f2bf(f.y); o.z = f2bf(f.z); o.w = f2bf(f.w);
      xbf4[i] = o;
    }
    return;
  }

  const int o = blockIdx.x;
  float Bo[R_DIM];
  #pragma unroll
  for (int r = 0; r < R_DIM; ++r) Bo[r] = Bw[o * R_DIM + r] * 2.0f;  // fold SCALING

  float ss = 0.f;
  #pragma unroll
  for (int g = 0; g < 4; ++g) {
    const int c = g * 256 + tid;                  // float4 column, coalesced
    float4 v = W4[(size_t)o * 1024 + c];
    #pragma unroll
    for (int r = 0; r < R_DIM; ++r) {
      const float4 a = Aw4[(size_t)r * 1024 + c];
      const float b = Bo[r];
      v.x += b * a.x; v.y += b * a.y; v.z += b * a.z; v.w += b * a.w;
    }
    ss += v.x * v.x + v.y * v.y + v.z * v.z + v.w * v.w;
    ushort4 ov;
    ov.x = f2bf(v.x); ov.y = f2bf(v.y); ov.z = f2bf(v.z); ov.w = f2bf(v.w);
    wbf4[(size_t)o * 1024 + c] = ov;
  }

  __shared__ float red[4];
  #pragma unroll
  for (int off = 32; off > 0; off >>= 1) ss += __shfl_down(ss, off, 64);
  if ((tid & 63) == 0) red[tid >> 6] = ss;
  __syncthreads();
  if (tid == 0)
    scale[o] = mag[o] / sqrtf(red[0] + red[1] + red[2] + red[3]);
}

// ------------- GEMM: C[m,n] = scale[n] * sum_k A[m,k]*Bt[n,k] -------------
// 256x256 tile, BK=64, 8 waves (2M x 4N), 512 threads. 8-phase schedule
// (T2 swizzle + T3/T4 counted vmcnt + T5 setprio + T1 XCD swizzle).
// LDS 128 KiB: A/B each 2(dbuf) x 2(half) x 128x64 bf16 sub-buffers.
//   A half h holds rows {0-63,128-191} (h=0) / {64-127,192-255} (h=1):
//     lrow = (r&63) + 64*(r>>7), h = (r>>6)&1  -> quadrant (mh) reads only A[mh].
//   B half h holds rows with ((r>>5)&1)==h: lrow = (r&31) + 64*(r>>6), h=(r>>5)&1.
// Stage slots per K-tile t:  P1:Ah1(t+1) P2:Bh1(t+1) P3:Ah0(t+2) P4:Bh0(t+2);
// vmcnt(4) once per tile at P4 -> all of t+1 resident, t+2's 2 half-tiles in flight.
// Source-swizzle (l&7)^(l>>3) on global col; reads use ((h*4+fq)^(fr&7)) ->
// conflict-free ds_read_b128 (verified 0 conflicts, prior session).
__global__ void __launch_bounds__(512, 2)
dora_gemm(const unsigned short* __restrict__ A,   // [M,K] bf16
          const unsigned short* __restrict__ Bt,  // [N,K] bf16
          const float* __restrict__ scale,        // [N]
          float* __restrict__ C) {                // [M,N] fp32
  __shared__ __align__(16) unsigned short As[2][2][128 * 64];
  __shared__ __align__(16) unsigned short Bs[2][2][128 * 64];

  const int tid  = threadIdx.x;
  const int lane = tid & 63;
  const int wave = tid >> 6;

  // T1: XCD-aware bijective swizzle. 512 wgs, 512 % 8 == 0.
  // XCD k owns a 4x16 panel of tiles -> per-K-step L2 working set ~640 KB.
  const int fid = blockIdx.y * gridDim.x + blockIdx.x;
  const int s   = (fid & 7) * 64 + (fid >> 3);
  const int bM  = (s >> 4) * 256;
  const int bN  = (s & 15) * 256;

  const int l3  = lane >> 3;            // 0..7
  const int l7  = lane & 7;
  const int swz = (l7 ^ l3) * 8;        // pre-swizzled source col (shorts)
  const int w8  = wave * 8;

  // staging base pointers (per-thread global, wave-uniform LDS dest)
  const unsigned short* srcA = A  + (size_t)(bM + w8 + l3) * K_DIM + swz;
  const unsigned short* srcB = Bt + (size_t)(bN + (wave & 3) * 8 + l3 + 64 * (wave >> 2)) * K_DIM + swz;

  // fragment read geometry
  const int fr   = lane & 15;
  const int fq   = lane >> 4;
  const int fr7  = fr & 7;
  const int arow = fr + 64 * (wave >> 2);   // + mt*16
  const int brow = fr + 32 * (wave & 3);    // + ntl*16

  f32x4 acc[8][4];
  #pragma unroll
  for (int i = 0; i < 8; ++i)
    #pragma unroll
    for (int j = 0; j < 4; ++j) acc[i][j] = (f32x4){0.f, 0.f, 0.f, 0.f};

  bf16x8 aF[4][2];      // current m-half A frags
  bf16x8 bF0[2][2];     // n-half 0 B frags (live P1->P3)
  bf16x8 bF1[2][2];     // n-half 1 B frags (live P2->P4)

#define STAGE_A(cc, hh, k0) do {                                              \
    gload16(srcA + (size_t)((hh) * 64)       * K_DIM + (k0), (unsigned short*)&As[cc][hh][w8 * 64]);        \
    gload16(srcA + (size_t)((hh) * 64 + 128) * K_DIM + (k0), (unsigned short*)&As[cc][hh][(64 + w8) * 64]); \
  } while (0)
#define STAGE_B(cc, hh, k0) do {                                              \
    gload16(srcB + (size_t)((hh) * 32)       * K_DIM + (k0), (unsigned short*)&Bs[cc][hh][w8 * 64]);        \
    gload16(srcB + (size_t)((hh) * 32 + 128) * K_DIM + (k0), (unsigned short*)&Bs[cc][hh][(64 + w8) * 64]); \
  } while (0)
#define LOAD_A(cc, mh) do {                                                   \
    _Pragma("unroll")                                                         \
    for (int mt = 0; mt < 4; ++mt) {                                          \
      _Pragma("unroll")                                                       \
      for (int h = 0; h < 2; ++h)                                             \
        aF[mt][h] = *(const bf16x8*)&As[cc][mh][(arow + mt * 16) * 64 + (((h * 4 + fq) ^ fr7) * 8)]; \
    }                                                                         \
  } while (0)
#define LOAD_B(cc, nh, dst) do {                                              \
    _Pragma("unroll")                                                         \
    for (int nt = 0; nt < 2; ++nt) {                                          \
      _Pragma("unroll")                                                       \
      for (int h = 0; h < 2; ++h)                                             \
        dst[nt][h] = *(const bf16x8*)&Bs[cc][nh][(brow + nt * 16) * 64 + (((h * 4 + fq) ^ fr7) * 8)]; \
    }                                                                         \
  } while (0)
#define MFMA_Q(mh, nh, bfr) do {                                              \
    _Pragma("unroll")                                                         \
    for (int mt = 0; mt < 4; ++mt) {                                          \
      _Pragma("unroll")                                                       \
      for (int nt = 0; nt < 2; ++nt) {                                        \
        _Pragma("unroll")                                                     \
        for (int h = 0; h < 2; ++h)                                           \
          acc[(mh) * 4 + mt][(nh) * 2 + nt] = __builtin_amdgcn_mfma_f32_16x16x32_bf16( \
              aF[mt][h], bfr[nt][h], acc[(mh) * 4 + mt][(nh) * 2 + nt], 0, 0, 0); \
      }                                                                       \
    }                                                                         \
  } while (0)
#define PH_SYNC_IN()  do { __builtin_amdgcn_s_barrier();                       \
    asm volatile("s_waitcnt lgkmcnt(0)" ::: "memory"); } while (0)

#define GROUP(cc, tt) do {                                                    \
    /* P1: quadrant (0,0) */                                                  \
    LOAD_A(cc, 0); LOAD_B(cc, 0, bF0);                                        \
    if ((tt) + 1 < NT) STAGE_A((cc) ^ 1, 1, ((tt) + 1) * 64);                 \
    PH_SYNC_IN();                                                             \
    __builtin_amdgcn_s_setprio(1); MFMA_Q(0, 0, bF0); __builtin_amdgcn_s_setprio(0); \
    __builtin_amdgcn_s_barrier();                                             \
    /* P2: quadrant (0,1) */                                                  \
    LOAD_B(cc, 1, bF1);                                                       \
    if ((tt) + 1 < NT) STAGE_B((cc) ^ 1, 1, ((tt) + 1) * 64);                 \
    PH_SYNC_IN();                                                             \
    __builtin_amdgcn_s_setprio(1); MFMA_Q(0, 1, bF1); __builtin_amdgcn_s_setprio(0); \
    __builtin_amdgcn_s_barrier();                                             \
    /* P3: quadrant (1,0) */                                                  \
    LOAD_A(cc, 1);                                                            \
    if ((tt) + 2 < NT) STAGE_A(cc, 0, ((tt) + 2) * 64);                       \
    PH_SYNC_IN();                                                             \
    __builtin_amdgcn_s_setprio(1); MFMA_Q(1, 0, bF0); __builtin_amdgcn_s_setprio(0); \
    __builtin_amdgcn_s_barrier();                                             \
    /* P4: quadrant (1,1) */                                                  \
    if ((tt) + 2 < NT) STAGE_B(cc, 0, ((tt) + 2) * 64);                       \
    PH_SYNC_IN();                                                             \
    __builtin_amdgcn_s_setprio(1); MFMA_Q(1, 1, bF1); __builtin_amdgcn_s_setprio(0); \
    if ((tt) < NT - 2) asm volatile("s_waitcnt vmcnt(4)" ::: "memory");       \
    else               asm volatile("s_waitcnt vmcnt(0)" ::: "memory");       \
    __builtin_amdgcn_s_barrier();                                             \
  } while (0)

  // prologue: tile 0 fully + Ah0/Bh0 of tile 1 (12 loads), keep 4 in flight
  STAGE_A(0, 0, 0); STAGE_B(0, 0, 0);
  STAGE_A(0, 1, 0); STAGE_B(0, 1, 0);
  STAGE_A(1, 0, 64); STAGE_B(1, 0, 64);
  asm volatile("s_waitcnt vmcnt(4)" ::: "memory");
  __builtin_amdgcn_s_barrier();

  for (int t = 0; t < NT; t += 2) {
    GROUP(0, t);
    GROUP(1, t + 1);
  }

#undef GROUP
#undef PH_SYNC_IN
#undef MFMA_Q
#undef LOAD_B
#undef LOAD_A
#undef STAGE_B
#undef STAGE_A

  // epilogue: C/D layout col=lane&15, row=(lane>>4)*4+reg  [m89]
  const int wMo = (wave >> 2) * 128;
  const int wNo = (wave & 3) * 64;
  float scv[4];
  #pragma unroll
  for (int fn = 0; fn < 4; ++fn) scv[fn] = scale[bN + wNo + fn * 16 + fr];
  #pragma unroll
  for (int fm = 0; fm < 8; ++fm) {
    const int m0 = bM + wMo + fm * 16 + fq * 4;
    #pragma unroll
    for (int fn = 0; fn < 4; ++fn) {
      const int n = bN + wNo + fn * 16 + fr;
      #pragma unroll
      for (int r = 0; r < 4; ++r)
        C[(size_t)(m0 + r) * N_DIM + n] = acc[fm][fn][r] * scv[fn];
    }
  }
}

extern "C" void kernel_launch(void* const* d_in, const int* in_sizes, int n_in,
                              void* d_out, int out_size, void* d_ws, size_t ws_size,
                              hipStream_t stream) {
  const float* x   = (const float*)d_in[0];   // [4,2048,4096]
  const float* W   = (const float*)d_in[1];   // [4096,4096]
  const float* la  = (const float*)d_in[2];   // [16,4096]
  const float* lb  = (const float*)d_in[3];   // [4096,16]
  const float* mag = (const float*)d_in[4];   // [4096]
  float* out = (float*)d_out;

  // ws: x_bf16 (64 MiB) | w_bf16 (32 MiB) | scale (16 KiB)
  unsigned short* xbf = (unsigned short*)d_ws;
  unsigned short* wbf = (unsigned short*)((char*)d_ws + (size_t)M_DIM * K_DIM * 2);
  float* scale = (float*)((char*)d_ws + (size_t)M_DIM * K_DIM * 2 + (size_t)N_DIM * K_DIM * 2);

  prep_kernel<<<WPREP_BLOCKS + CAST_BLOCKS, 256, 0, stream>>>(
      (const float4*)x, (ushort4*)xbf, (const float4*)W, (const float4*)la,
      lb, mag, (ushort4*)wbf, scale);
  dim3 grid(N_DIM / 256, M_DIM / 256);
  dora_gemm<<<grid, 512, 0, stream>>>(xbf, wbf, scale, out);
}